// Round 6
// baseline (219.463 us; speedup 1.0000x reference)
//
#include <hip/hip_runtime.h>

#pragma clang fp contract(off)

#define HH 1024
#define WW 1024
#define HWSZ (HH * WW)
#define NB 16
#define CHUNKS 128                       // blocks per batch
#define THREADS 256
#define PIX_PER_BLOCK (HWSZ / CHUNKS)    // 8192
#define ITERS (PIX_PER_BLOCK / (THREADS * 4))  // 8
#define NBLK (CHUNKS * NB)               // 2048 stage-1 blocks
#define TPAD 8                           // zero-padding offset in tile
#define TDIM 32                          // tile dim, window covers [-8,24)
#define TSTRIDE 37                       // row stride in floats; 37%32=5 spreads banks
#define PLANE (TDIM * TSTRIDE)           // 1184 floats per channel plane

typedef float f32x2 __attribute__((ext_vector_type(2)));

// ---- VOP3P packed fp32 helpers (two independent IEEE fp32 ops per inst) ----
__device__ __forceinline__ f32x2 pk_fma(f32x2 a, f32x2 b, f32x2 c) {
  f32x2 d;
  asm("v_pk_fma_f32 %0, %1, %2, %3" : "=v"(d) : "v"(a), "v"(b), "v"(c));
  return d;
}
__device__ __forceinline__ f32x2 pk_mul(f32x2 a, f32x2 b) {
  f32x2 d;
  asm("v_pk_mul_f32 %0, %1, %2" : "=v"(d) : "v"(a), "v"(b));
  return d;
}
__device__ __forceinline__ f32x2 pk_add(f32x2 a, f32x2 b) {
  f32x2 d;
  asm("v_pk_add_f32 %0, %1, %2" : "=v"(d) : "v"(a), "v"(b));
  return d;
}
__device__ __forceinline__ f32x2 pk_sub(f32x2 a, f32x2 b) {  // a - b
  f32x2 d;
  asm("v_pk_add_f32 %0, %1, %2 neg_lo:[0,1] neg_hi:[0,1]"
      : "=v"(d) : "v"(a), "v"(b));
  return d;
}
// fma(a, b, -c)
__device__ __forceinline__ f32x2 pk_fma_negc(f32x2 a, f32x2 b, f32x2 c) {
  f32x2 d;
  asm("v_pk_fma_f32 %0, %1, %2, %3 neg_lo:[0,0,1] neg_hi:[0,0,1]"
      : "=v"(d) : "v"(a), "v"(b), "v"(c));
  return d;
}
// (a.lo*b.lo, a.hi*b.lo)  -- src1 broadcasts its LOW half
__device__ __forceinline__ f32x2 pk_mul_blo(f32x2 a, f32x2 b) {
  f32x2 d;
  asm("v_pk_mul_f32 %0, %1, %2 op_sel:[0,0] op_sel_hi:[1,0]"
      : "=v"(d) : "v"(a), "v"(b));
  return d;
}
// (a.lo*b.hi, a.hi*b.hi)  -- src1 broadcasts its HIGH half
__device__ __forceinline__ f32x2 pk_mul_bhi(f32x2 a, f32x2 b) {
  f32x2 d;
  asm("v_pk_mul_f32 %0, %1, %2 op_sel:[0,1] op_sel_hi:[1,1]"
      : "=v"(d) : "v"(a), "v"(b));
  return d;
}

// Faithful grid_sample corner path (zeros padding), reads global. Essentially
// never executed for this data (|v| <= ~7 => in-window), but guarantees
// correctness for arbitrary coords.
__device__ __attribute__((noinline)) float2 bilin_global(
    const float* __restrict__ p0, const float* __restrict__ p1,
    float x, float y) {
  float x0f = floorf(x), y0f = floorf(y);
  float wx = x - x0f, wy = y - y0f;
  float u0 = 1.f - wx, v0 = 1.f - wy;
  int ix = (int)x0f, iy = (int)y0f;
  float rx = 0.f, ry = 0.f;
  const int cxs[2] = {ix, ix + 1};
  const int cys[2] = {iy, iy + 1};
  const float wxs[2] = {u0, wx};
  const float wys[2] = {v0, wy};
#pragma unroll
  for (int jy = 0; jy < 2; jy++)
#pragma unroll
    for (int jx = 0; jx < 2; jx++) {
      int cx = cxs[jx], cy = cys[jy];
      bool inb = (cx >= 0) & (cx < WW) & (cy >= 0) & (cy < HH);
      int ccx = min(max(cx, 0), WW - 1);
      int ccy = min(max(cy, 0), HH - 1);
      float wm = (wxs[jx] * wys[jy]) * (inb ? 1.f : 0.f);
      rx += p0[ccy * WW + ccx] * wm;
      ry += p1[ccy * WW + ccx] * wm;
    }
  return make_float2(rx, ry);
}

// Fast path: zero-padded planes, window [-8,24)^2 at plane[(y+8)*37+(x+8)].
// Weights via op_sel broadcasts; interp packed against the natural ds_read2
// pairs (a00,a10)/(a01,a11). Per-component IEEE semantics identical to the
// scalar version that passed absmax=0.
__device__ __forceinline__ void sample_pk(
    const float* __restrict__ t0, const float* __restrict__ t1,
    f32x2 xy, f32x2 v, float& accx, float& accy) {
  float fx = floorf(xy.x), fy = floorf(xy.y);
  f32x2 P, Pv;                  // P=(u0,wx), Pv=(v0,wy)
  P.y = xy.x - fx;
  P.x = 1.0f - P.y;
  Pv.y = xy.y - fy;
  Pv.x = 1.0f - Pv.y;
  int idx = (int)fmaf(fy, (float)TSTRIDE, fx) + (TPAD * TSTRIDE + TPAD);
  f32x2 WP0 = pk_mul_blo(P, Pv);  // (w00,w10) = (u0*v0, wx*v0)
  f32x2 WP1 = pk_mul_bhi(P, Pv);  // (w01,w11) = (u0*wy, wx*wy)
  f32x2 A0, A1, B0, B1;
  A0.x = t0[idx];           A0.y = t0[idx + 1];
  A1.x = t0[idx + TSTRIDE]; A1.y = t0[idx + TSTRIDE + 1];
  B0.x = t1[idx];           B0.y = t1[idx + 1];
  B1.x = t1[idx + TSTRIDE]; B1.y = t1[idx + TSTRIDE + 1];
  f32x2 AC = pk_fma(A1, WP1, pk_mul(A0, WP0));
  f32x2 BC = pk_fma(B1, WP1, pk_mul(B0, WP0));
  float rx = AC.x + AC.y;
  float ry = BC.x + BC.y;
  accx += fabsf(rx - v.x);
  accy += fabsf(ry - v.y);
}

__global__ __launch_bounds__(THREADS) void gs_diff_kernel(
    const float* __restrict__ in, double* __restrict__ partial) {
  const int b = blockIdx.y;
  const int chunk = blockIdx.x;
  const float* p0 = in + (size_t)b * (2 * HWSZ);
  const float* p1 = p0 + HWSZ;

  __shared__ float tile0[PLANE];
  __shared__ float tile1[PLANE];
  const int t = threadIdx.x;
#pragma unroll
  for (int i = t; i < TDIM * TDIM; i += THREADS) {
    int py = i >> 5, px = i & 31;
    float a = 0.f, c = 0.f;
    if (py >= TPAD && px >= TPAD) {
      int yy = py - TPAD, xx = px - TPAD;
      a = p0[yy * WW + xx];
      c = p1[yy * WW + xx];
    }
    tile0[py * TSTRIDE + px] = a;
    tile1[py * TSTRIDE + px] = c;
  }
  __syncthreads();

  // hoisted constant pairs for VOP3P (loop-invariant)
  const f32x2 KR    = {(float)(1.0 / 1023.0), (float)(1.0 / 1023.0)};
  const f32x2 KN    = {-1023.0f, -1023.0f};
  const f32x2 K512I = {1.0f / 512.0f, 1.0f / 512.0f};
  const f32x2 K1024I= {1.0f / 1024.0f, 1.0f / 1024.0f};
  const f32x2 K1    = {1.0f, 1.0f};
  const f32x2 K2    = {2.0f, 2.0f};
  const f32x2 K512  = {512.0f, 512.0f};
  const f32x2 KMH   = {-0.5f, -0.5f};
  const f32x2 K5115 = {511.5f, 511.5f};

  float acc0x = 0.f, acc0y = 0.f, acc1x = 0.f, acc1y = 0.f;
  float acc2x = 0.f, acc2y = 0.f, acc3x = 0.f, acc3y = 0.f;
  int base = chunk * PIX_PER_BLOCK + t * 4;

  // Coordinate math bit-exact vs reference (validated rounds 4/5):
  //   s1 = fma(v, 1/512, 1/1024); t1 = (s1-1)+1
  //   q  = v/1023 correctly rounded (2-step Markstein); t2 = fma(q,2,-1)+1
  //   x1 = fma(t1,512,-0.5); x2 = t2*511.5; x3 = t1*511.5; x4 = fma(t2,512,-0.5)
#define PIXEL(vx, vy, ACCX0, ACCY0, ACCX1, ACCY1, ACCX2, ACCY2, ACCX3, ACCY3) \
  {                                                                          \
    f32x2 V; V.x = (vx); V.y = (vy);                                         \
    f32x2 Q = pk_mul(V, KR);                                                 \
    Q = pk_fma(pk_fma(KN, Q, V), KR, Q);                                     \
    Q = pk_fma(pk_fma(KN, Q, V), KR, Q);                                     \
    f32x2 S1 = pk_fma(V, K512I, K1024I);                                     \
    f32x2 T1 = pk_add(pk_sub(S1, K1), K1);                                   \
    f32x2 T2 = pk_add(pk_fma_negc(Q, K2, K1), K1);                           \
    f32x2 XY1 = pk_fma(T1, K512, KMH);                                       \
    f32x2 XY2 = pk_mul(T2, K5115);                                           \
    f32x2 XY3 = pk_mul(T1, K5115);                                           \
    f32x2 XY4 = pk_fma(T2, K512, KMH);                                       \
    float av = fmaxf(fabsf((vx)), fabsf((vy)));                              \
    /* |v|<=7 => every coord in [-7.6,21.6] subset of window [-8,23) */      \
    if (__builtin_expect(av > 7.0f, 0)) {                                    \
      float2 r;                                                              \
      r = bilin_global(p0, p1, XY1.x, XY1.y);                                \
      ACCX0 += fabsf(r.x - (vx)); ACCY0 += fabsf(r.y - (vy));                \
      r = bilin_global(p0, p1, XY2.x, XY2.y);                                \
      ACCX1 += fabsf(r.x - (vx)); ACCY1 += fabsf(r.y - (vy));                \
      r = bilin_global(p0, p1, XY3.x, XY3.y);                                \
      ACCX2 += fabsf(r.x - (vx)); ACCY2 += fabsf(r.y - (vy));                \
      r = bilin_global(p0, p1, XY4.x, XY4.y);                                \
      ACCX3 += fabsf(r.x - (vx)); ACCY3 += fabsf(r.y - (vy));                \
    } else {                                                                 \
      sample_pk(tile0, tile1, XY1, V, ACCX0, ACCY0);                         \
      sample_pk(tile0, tile1, XY2, V, ACCX1, ACCY1);                         \
      sample_pk(tile0, tile1, XY3, V, ACCX2, ACCY2);                         \
      sample_pk(tile0, tile1, XY4, V, ACCX3, ACCY3);                         \
    }                                                                        \
  }

  for (int j = 0; j < ITERS; j++, base += THREADS * 4) {
    float4 X = *(const float4*)(p0 + base);
    float4 Y = *(const float4*)(p1 + base);
    PIXEL(X.x, Y.x, acc0x, acc0y, acc1x, acc1y, acc2x, acc2y, acc3x, acc3y);
    PIXEL(X.y, Y.y, acc0x, acc0y, acc1x, acc1y, acc2x, acc2y, acc3x, acc3y);
    PIXEL(X.z, Y.z, acc0x, acc0y, acc1x, acc1y, acc2x, acc2y, acc3x, acc3y);
    PIXEL(X.w, Y.w, acc0x, acc0y, acc1x, acc1y, acc2x, acc2y, acc3x, acc3y);
  }
#undef PIXEL

  float acc0 = acc0x + acc0y, acc1 = acc1x + acc1y;
  float acc2 = acc2x + acc2y, acc3 = acc3x + acc3y;

  // wave(64) butterfly reduce, then cross-wave via LDS
#pragma unroll
  for (int m = 1; m < 64; m <<= 1) {
    acc0 += __shfl_xor(acc0, m, 64);
    acc1 += __shfl_xor(acc1, m, 64);
    acc2 += __shfl_xor(acc2, m, 64);
    acc3 += __shfl_xor(acc3, m, 64);
  }
  __shared__ float wpart[4][4];  // [wave][variant]
  int lane = t & 63, wid = t >> 6;
  if (lane == 0) {
    wpart[wid][0] = acc0;
    wpart[wid][1] = acc1;
    wpart[wid][2] = acc2;
    wpart[wid][3] = acc3;
  }
  __syncthreads();
  if (t < 4) {
    double s = (double)wpart[0][t] + (double)wpart[1][t] +
               (double)wpart[2][t] + (double)wpart[3][t];
    partial[t * NBLK + blockIdx.y * CHUNKS + blockIdx.x] = s;
  }
}

__global__ __launch_bounds__(256) void gs_reduce_kernel(
    const double* __restrict__ partial, float* __restrict__ out) {
  const int v = blockIdx.x;  // variant 0..3
  const int t = threadIdx.x;
  double s = 0.0;
  for (int i = t; i < NBLK; i += 256) s += partial[v * NBLK + i];
#pragma unroll
  for (int m = 1; m < 64; m <<= 1) s += __shfl_xor(s, m, 64);
  __shared__ double ws[4];
  if ((t & 63) == 0) ws[t >> 6] = s;
  __syncthreads();
  if (t == 0) out[v] = (float)(ws[0] + ws[1] + ws[2] + ws[3]);
}

extern "C" void kernel_launch(void* const* d_in, const int* in_sizes, int n_in,
                              void* d_out, int out_size, void* d_ws,
                              size_t ws_size, hipStream_t stream) {
  const float* in = (const float*)d_in[0];
  float* out = (float*)d_out;
  double* partial = (double*)d_ws;  // 4 * 2048 doubles = 64 KiB

  dim3 g1(CHUNKS, NB);
  gs_diff_kernel<<<g1, THREADS, 0, stream>>>(in, partial);
  gs_reduce_kernel<<<4, 256, 0, stream>>>(partial, out);
}

// Round 7
// 212.358 us; speedup vs baseline: 1.0335x; 1.0335x over previous
//
#include <hip/hip_runtime.h>

#pragma clang fp contract(off)

#define HH 1024
#define WW 1024
#define HWSZ (HH * WW)
#define NB 16
#define CHUNKS 256                       // blocks per batch
#define THREADS 256
#define PIX_PER_BLOCK (HWSZ / CHUNKS)    // 4096
#define ITERS (PIX_PER_BLOCK / (THREADS * 4))  // 4
#define NBLK (CHUNKS * NB)               // 4096 stage-1 blocks
#define TPAD 8                           // zero-padding offset in window
#define TDIM 32                          // window [-8,24)^2
#define TSTRIDE 37                       // entry stride per row (37%32=5)
#define PLANE (TDIM * TSTRIDE)           // 1184 f32x4 entries = 18944 B LDS

typedef float f32x2 __attribute__((ext_vector_type(2)));
typedef float f32x4 __attribute__((ext_vector_type(4)));

// ---- VOP3P packed fp32 helpers (two independent IEEE fp32 ops per inst) ----
__device__ __forceinline__ f32x2 pk_fma(f32x2 a, f32x2 b, f32x2 c) {
  f32x2 d;
  asm("v_pk_fma_f32 %0, %1, %2, %3" : "=v"(d) : "v"(a), "v"(b), "v"(c));
  return d;
}
__device__ __forceinline__ f32x2 pk_mul(f32x2 a, f32x2 b) {
  f32x2 d;
  asm("v_pk_mul_f32 %0, %1, %2" : "=v"(d) : "v"(a), "v"(b));
  return d;
}
__device__ __forceinline__ f32x2 pk_add(f32x2 a, f32x2 b) {
  f32x2 d;
  asm("v_pk_add_f32 %0, %1, %2" : "=v"(d) : "v"(a), "v"(b));
  return d;
}
__device__ __forceinline__ f32x2 pk_sub(f32x2 a, f32x2 b) {  // a - b
  f32x2 d;
  asm("v_pk_add_f32 %0, %1, %2 neg_lo:[0,1] neg_hi:[0,1]"
      : "=v"(d) : "v"(a), "v"(b));
  return d;
}
// fma(a, b, -c)
__device__ __forceinline__ f32x2 pk_fma_negc(f32x2 a, f32x2 b, f32x2 c) {
  f32x2 d;
  asm("v_pk_fma_f32 %0, %1, %2, %3 neg_lo:[0,0,1] neg_hi:[0,0,1]"
      : "=v"(d) : "v"(a), "v"(b), "v"(c));
  return d;
}
// (a.lo*b.lo, a.hi*b.lo)
__device__ __forceinline__ f32x2 pk_mul_blo(f32x2 a, f32x2 b) {
  f32x2 d;
  asm("v_pk_mul_f32 %0, %1, %2 op_sel:[0,0] op_sel_hi:[1,0]"
      : "=v"(d) : "v"(a), "v"(b));
  return d;
}
// (a.lo*b.hi, a.hi*b.hi)
__device__ __forceinline__ f32x2 pk_mul_bhi(f32x2 a, f32x2 b) {
  f32x2 d;
  asm("v_pk_mul_f32 %0, %1, %2 op_sel:[0,1] op_sel_hi:[1,1]"
      : "=v"(d) : "v"(a), "v"(b));
  return d;
}
// P = (1-F.lo, F.lo): lo = -F.lo + K10.lo(=1.0); hi = F.lo + K10.hi(=0.0)
__device__ __forceinline__ f32x2 pk_wpair_lo(f32x2 F, f32x2 K10) {
  f32x2 d;
  asm("v_pk_add_f32 %0, %1, %2 op_sel:[0,0] op_sel_hi:[0,1] neg_lo:[1,0] neg_hi:[0,0]"
      : "=v"(d) : "v"(F), "v"(K10));
  return d;
}
// Pv = (1-F.hi, F.hi)
__device__ __forceinline__ f32x2 pk_wpair_hi(f32x2 F, f32x2 K10) {
  f32x2 d;
  asm("v_pk_add_f32 %0, %1, %2 op_sel:[1,0] op_sel_hi:[1,1] neg_lo:[1,0] neg_hi:[0,0]"
      : "=v"(d) : "v"(F), "v"(K10));
  return d;
}

// Correctly-rounded x/1023 via 2-step fma refinement (scalar, slow path only).
__device__ __forceinline__ float div1023s(float x) {
  const float r = (float)(1.0 / 1023.0);
  float q = x * r;
  float e = fmaf(-1023.0f, q, x);
  q = fmaf(e, r, q);
  e = fmaf(-1023.0f, q, x);
  q = fmaf(e, r, q);
  return q;
}

// Faithful grid_sample corner path (zeros padding), reads global. Essentially
// never executed (|v| <= ~7 => in-window), but guarantees correctness.
__device__ __attribute__((noinline)) float2 bilin_global(
    const float* __restrict__ p0, const float* __restrict__ p1,
    float x, float y) {
  float x0f = floorf(x), y0f = floorf(y);
  float wx = x - x0f, wy = y - y0f;
  float u0 = 1.f - wx, v0 = 1.f - wy;
  int ix = (int)x0f, iy = (int)y0f;
  float rx = 0.f, ry = 0.f;
  const int cxs[2] = {ix, ix + 1};
  const int cys[2] = {iy, iy + 1};
  const float wxs[2] = {u0, wx};
  const float wys[2] = {v0, wy};
#pragma unroll
  for (int jy = 0; jy < 2; jy++)
#pragma unroll
    for (int jx = 0; jx < 2; jx++) {
      int cx = cxs[jx], cy = cys[jy];
      bool inb = (cx >= 0) & (cx < WW) & (cy >= 0) & (cy < HH);
      int ccx = min(max(cx, 0), WW - 1);
      int ccy = min(max(cy, 0), HH - 1);
      float wm = (wxs[jx] * wys[jy]) * (inb ? 1.f : 0.f);
      rx += p0[ccy * WW + ccx] * wm;
      ry += p1[ccy * WW + ccx] * wm;
    }
  return make_float2(rx, ry);
}

// Fast path: one ds_read_b128 per row delivers (a_x, a_x1, b_x, b_x1) for
// both channels; row+1 is the same vaddr at immediate offset 37*16=592 B.
// Weight/interp per-component IEEE ops identical to the absmax=0.0 version.
__device__ __forceinline__ void sample4(
    const f32x4* __restrict__ ent, f32x2 xy, f32x2 v, f32x2 K10,
    float& accx, float& accy) {
  float fx = floorf(xy.x), fy = floorf(xy.y);
  f32x2 F;
  F.x = xy.x - fx;   // wx
  F.y = xy.y - fy;   // wy
  int idx = (int)fmaf(fy, (float)TSTRIDE, fx) + (TPAD * TSTRIDE + TPAD);
  f32x2 P  = pk_wpair_lo(F, K10);   // (u0, wx)
  f32x2 Pv = pk_wpair_hi(F, K10);   // (v0, wy)
  f32x2 WP0 = pk_mul_blo(P, Pv);    // (w00, w10)
  f32x2 WP1 = pk_mul_bhi(P, Pv);    // (w01, w11)
  f32x4 R0 = ent[idx];              // (a00, a10, b00, b10)
  f32x4 R1 = ent[idx + TSTRIDE];    // (a01, a11, b01, b11)
  f32x2 A0; A0.x = R0.x; A0.y = R0.y;
  f32x2 B0; B0.x = R0.z; B0.y = R0.w;
  f32x2 A1; A1.x = R1.x; A1.y = R1.y;
  f32x2 B1; B1.x = R1.z; B1.y = R1.w;
  f32x2 AC = pk_fma(A1, WP1, pk_mul(A0, WP0));
  f32x2 BC = pk_fma(B1, WP1, pk_mul(B0, WP0));
  accx += fabsf((AC.x + AC.y) - v.x);
  accy += fabsf((BC.x + BC.y) - v.y);
}

__global__ __launch_bounds__(THREADS, 6) void gs_diff_kernel(
    const float* __restrict__ in, double* __restrict__ partial) {
  const int b = blockIdx.y;
  const int chunk = blockIdx.x;
  const float* p0 = in + (size_t)b * (2 * HWSZ);
  const float* p1 = p0 + HWSZ;

  __shared__ f32x4 ent[PLANE];
  const int t = threadIdx.x;
#pragma unroll
  for (int i = t; i < TDIM * TDIM; i += THREADS) {
    int py = i >> 5, px = i & 31;
    float a0 = 0.f, a1 = 0.f, b0 = 0.f, b1 = 0.f;
    int yy = py - TPAD, xx = px - TPAD;
    if (py >= TPAD) {
      const float* r0 = p0 + yy * WW;
      const float* r1 = p1 + yy * WW;
      if (px >= TPAD)                   { a0 = r0[xx];     b0 = r1[xx]; }
      if (px >= TPAD - 1 && px < TDIM - 1) { a1 = r0[xx + 1]; b1 = r1[xx + 1]; }
    }
    f32x4 e; e.x = a0; e.y = a1; e.z = b0; e.w = b1;
    ent[py * TSTRIDE + px] = e;
  }
  __syncthreads();

  // hoisted constant pairs for VOP3P (loop-invariant)
  const f32x2 KR    = {(float)(1.0 / 1023.0), (float)(1.0 / 1023.0)};
  const f32x2 KN    = {-1023.0f, -1023.0f};
  const f32x2 K512I = {1.0f / 512.0f, 1.0f / 512.0f};
  const f32x2 K1024I= {1.0f / 1024.0f, 1.0f / 1024.0f};
  const f32x2 K1    = {1.0f, 1.0f};
  const f32x2 K2    = {2.0f, 2.0f};
  const f32x2 K512  = {512.0f, 512.0f};
  const f32x2 KMH   = {-0.5f, -0.5f};
  const f32x2 K5115 = {511.5f, 511.5f};
  const f32x2 K10   = {1.0f, 0.0f};

  float acc0x = 0.f, acc0y = 0.f, acc1x = 0.f, acc1y = 0.f;
  float acc2x = 0.f, acc2y = 0.f, acc3x = 0.f, acc3y = 0.f;

  const float* px_ = p0 + chunk * PIX_PER_BLOCK + t * 4;
  const float* py_ = p1 + chunk * PIX_PER_BLOCK + t * 4;

  // Coordinate math bit-exact vs reference (validated rounds 4-6):
  //   s1 = fma(v, 1/512, 1/1024); t1 = (s1-1)+1
  //   q  = v/1023 correctly rounded; t2 = fma(q,2,-1)+1
  //   x1 = fma(t1,512,-0.5); x2 = t2*511.5; x3 = t1*511.5; x4 = fma(t2,512,-0.5)
#define PIXEL_FAST(vx, vy)                                                   \
  {                                                                          \
    f32x2 V; V.x = (vx); V.y = (vy);                                         \
    f32x2 Q = pk_mul(V, KR);                                                 \
    Q = pk_fma(pk_fma(KN, Q, V), KR, Q);                                     \
    Q = pk_fma(pk_fma(KN, Q, V), KR, Q);                                     \
    f32x2 S1 = pk_fma(V, K512I, K1024I);                                     \
    f32x2 T1 = pk_add(pk_sub(S1, K1), K1);                                   \
    f32x2 T2 = pk_add(pk_fma_negc(Q, K2, K1), K1);                           \
    f32x2 XY1 = pk_fma(T1, K512, KMH);                                       \
    f32x2 XY2 = pk_mul(T2, K5115);                                           \
    f32x2 XY3 = pk_mul(T1, K5115);                                           \
    f32x2 XY4 = pk_fma(T2, K512, KMH);                                       \
    sample4(ent, XY1, V, K10, acc0x, acc0y);                                 \
    sample4(ent, XY2, V, K10, acc1x, acc1y);                                 \
    sample4(ent, XY3, V, K10, acc2x, acc2y);                                 \
    sample4(ent, XY4, V, K10, acc3x, acc3y);                                 \
  }

#define PIXEL_SLOW(vx, vy)                                                   \
  {                                                                          \
    float s1x = fmaf((vx), (1.0f / 512.0f), (1.0f / 1024.0f));               \
    float t1x = (s1x - 1.0f) + 1.0f;                                         \
    float s1y = fmaf((vy), (1.0f / 512.0f), (1.0f / 1024.0f));               \
    float t1y = (s1y - 1.0f) + 1.0f;                                         \
    float s2x = div1023s(vx);                                                \
    float t2x = fmaf(s2x, 2.0f, -1.0f) + 1.0f;                               \
    float s2y = div1023s(vy);                                                \
    float t2y = fmaf(s2y, 2.0f, -1.0f) + 1.0f;                               \
    float x1 = fmaf(t1x, 512.0f, -0.5f);                                     \
    float y1 = fmaf(t1y, 512.0f, -0.5f);                                     \
    float x2 = t2x * 511.5f;                                                 \
    float y2 = t2y * 511.5f;                                                 \
    float x3 = t1x * 511.5f;                                                 \
    float y3 = t1y * 511.5f;                                                 \
    float x4 = fmaf(t2x, 512.0f, -0.5f);                                     \
    float y4 = fmaf(t2y, 512.0f, -0.5f);                                     \
    float2 r;                                                                \
    r = bilin_global(p0, p1, x1, y1);                                        \
    acc0x += fabsf(r.x - (vx)); acc0y += fabsf(r.y - (vy));                  \
    r = bilin_global(p0, p1, x2, y2);                                        \
    acc1x += fabsf(r.x - (vx)); acc1y += fabsf(r.y - (vy));                  \
    r = bilin_global(p0, p1, x3, y3);                                        \
    acc2x += fabsf(r.x - (vx)); acc2y += fabsf(r.y - (vy));                  \
    r = bilin_global(p0, p1, x4, y4);                                        \
    acc3x += fabsf(r.x - (vx)); acc3y += fabsf(r.y - (vy));                  \
  }

  float4 X = *(const float4*)px_;
  float4 Y = *(const float4*)py_;
  for (int j = 0; j < ITERS; j++) {
    float4 Xn, Yn;
    if (j < ITERS - 1) {  // register prefetch of next iteration's pixels
      Xn = *(const float4*)(px_ + (j + 1) * (THREADS * 4));
      Yn = *(const float4*)(py_ + (j + 1) * (THREADS * 4));
    }
    // one range check per 4 pixels: |v|<=7 => all coords in [-7.6,21.6]
    float m8 = fmaxf(
        fmaxf(fmaxf(fabsf(X.x), fabsf(X.y)), fmaxf(fabsf(X.z), fabsf(X.w))),
        fmaxf(fmaxf(fabsf(Y.x), fabsf(Y.y)), fmaxf(fabsf(Y.z), fabsf(Y.w))));
    if (__builtin_expect(m8 > 7.0f, 0)) {
      PIXEL_SLOW(X.x, Y.x);
      PIXEL_SLOW(X.y, Y.y);
      PIXEL_SLOW(X.z, Y.z);
      PIXEL_SLOW(X.w, Y.w);
    } else {
      PIXEL_FAST(X.x, Y.x);
      PIXEL_FAST(X.y, Y.y);
      PIXEL_FAST(X.z, Y.z);
      PIXEL_FAST(X.w, Y.w);
    }
    if (j < ITERS - 1) { X = Xn; Y = Yn; }
  }
#undef PIXEL_FAST
#undef PIXEL_SLOW

  float acc0 = acc0x + acc0y, acc1 = acc1x + acc1y;
  float acc2 = acc2x + acc2y, acc3 = acc3x + acc3y;

  // wave(64) butterfly reduce, then cross-wave via LDS
#pragma unroll
  for (int m = 1; m < 64; m <<= 1) {
    acc0 += __shfl_xor(acc0, m, 64);
    acc1 += __shfl_xor(acc1, m, 64);
    acc2 += __shfl_xor(acc2, m, 64);
    acc3 += __shfl_xor(acc3, m, 64);
  }
  __shared__ float wpart[4][4];  // [wave][variant]
  int lane = t & 63, wid = t >> 6;
  if (lane == 0) {
    wpart[wid][0] = acc0;
    wpart[wid][1] = acc1;
    wpart[wid][2] = acc2;
    wpart[wid][3] = acc3;
  }
  __syncthreads();
  if (t < 4) {
    double s = (double)wpart[0][t] + (double)wpart[1][t] +
               (double)wpart[2][t] + (double)wpart[3][t];
    partial[t * NBLK + blockIdx.y * CHUNKS + blockIdx.x] = s;
  }
}

__global__ __launch_bounds__(256) void gs_reduce_kernel(
    const double* __restrict__ partial, float* __restrict__ out) {
  const int v = blockIdx.x;  // variant 0..3
  const int t = threadIdx.x;
  double s = 0.0;
  for (int i = t; i < NBLK; i += 256) s += partial[v * NBLK + i];
#pragma unroll
  for (int m = 1; m < 64; m <<= 1) s += __shfl_xor(s, m, 64);
  __shared__ double ws[4];
  if ((t & 63) == 0) ws[t >> 6] = s;
  __syncthreads();
  if (t == 0) out[v] = (float)(ws[0] + ws[1] + ws[2] + ws[3]);
}

extern "C" void kernel_launch(void* const* d_in, const int* in_sizes, int n_in,
                              void* d_out, int out_size, void* d_ws,
                              size_t ws_size, hipStream_t stream) {
  const float* in = (const float*)d_in[0];
  float* out = (float*)d_out;
  double* partial = (double*)d_ws;  // 4 * 4096 doubles = 128 KiB

  dim3 g1(CHUNKS, NB);
  gs_diff_kernel<<<g1, THREADS, 0, stream>>>(in, partial);
  gs_reduce_kernel<<<4, 256, 0, stream>>>(partial, out);
}